// Round 1
// baseline (54.065 us; speedup 1.0000x reference)
//
#include <hip/hip_runtime.h>

constexpr int N_TOKENS   = 65536;
constexpr int N_FEATURES = 8;
constexpr int VOCAB      = 1026;
constexpr int EMB_DIM    = 256;

// One thread owns one (token, 4-dim chunk). 64 threads (one wave) per token:
// gather index is wave-uniform -> each row gather is a contiguous 1 KiB load.
__global__ __launch_bounds__(256) void emb_gather_sum(
    const int*   __restrict__ indices,   // [N_TOKENS][N_FEATURES]
    const float* __restrict__ tables,    // [N_FEATURES][VOCAB][EMB_DIM]
    float*       __restrict__ out)       // [N_TOKENS][EMB_DIM]
{
    const int gid = blockIdx.x * blockDim.x + threadIdx.x;
    const int t   = gid >> 6;            // token (wave-uniform)
    const int c   = (gid & 63) << 2;     // dim offset 0..252, float4-aligned
    if (t >= N_TOKENS) return;

    const int* __restrict__ idx = indices + t * N_FEATURES;

    float4 acc = make_float4(0.f, 0.f, 0.f, 0.f);
#pragma unroll
    for (int f = 0; f < N_FEATURES; ++f) {
        const int ix = idx[f];           // wave-uniform broadcast load
        const float4 v = *reinterpret_cast<const float4*>(
            tables + ((size_t)f * VOCAB + (size_t)ix) * EMB_DIM + c);
        acc.x += v.x; acc.y += v.y; acc.z += v.z; acc.w += v.w;
    }

    *reinterpret_cast<float4*>(out + (size_t)t * EMB_DIM + c) = acc;
}

extern "C" void kernel_launch(void* const* d_in, const int* in_sizes, int n_in,
                              void* d_out, int out_size, void* d_ws, size_t ws_size,
                              hipStream_t stream) {
    const int*   indices = (const int*)d_in[0];
    const float* tables  = (const float*)d_in[1];
    float*       out     = (float*)d_out;

    const int total_threads = N_TOKENS * 64;      // 4,194,304
    const int block = 256;
    const int grid  = total_threads / block;      // 16384
    emb_gather_sum<<<grid, block, 0, stream>>>(indices, tables, out);
}

// Round 2
// 36.384 us; speedup vs baseline: 1.4859x; 1.4859x over previous
//
#include <hip/hip_runtime.h>

constexpr int N_TOKENS   = 65536;
constexpr int N_FEATURES = 8;
constexpr int VOCAB      = 1026;
constexpr int EMB_DIM    = 256;
constexpr int TABLE_ELEMS = N_FEATURES * VOCAB * EMB_DIM;   // 2,101,248

// ---------- prep: fp32 table -> bf16 (RNE) into workspace ----------
__global__ __launch_bounds__(256) void cvt_table_bf16(
    const float* __restrict__ src, unsigned short* __restrict__ dst, int n)
{
    int i = (blockIdx.x * blockDim.x + threadIdx.x) * 4;
    if (i + 3 >= n) {
        for (int k = 0; i + k < n; ++k) {
            unsigned int x = __float_as_uint(src[i + k]);
            unsigned int r = x + 0x7FFFu + ((x >> 16) & 1u);
            dst[i + k] = (unsigned short)(r >> 16);
        }
        return;
    }
    const float4 v = *reinterpret_cast<const float4*>(src + i);
    ushort4 o;
    unsigned int x;
    x = __float_as_uint(v.x); o.x = (unsigned short)((x + 0x7FFFu + ((x >> 16) & 1u)) >> 16);
    x = __float_as_uint(v.y); o.y = (unsigned short)((x + 0x7FFFu + ((x >> 16) & 1u)) >> 16);
    x = __float_as_uint(v.z); o.z = (unsigned short)((x + 0x7FFFu + ((x >> 16) & 1u)) >> 16);
    x = __float_as_uint(v.w); o.w = (unsigned short)((x + 0x7FFFu + ((x >> 16) & 1u)) >> 16);
    *reinterpret_cast<ushort4*>(dst + i) = o;
}

// ---------- main: gather-sum from bf16 table ----------
// One thread per (token, 4-dim chunk); 64 lanes (one wave) share a token so
// every row gather is a contiguous, coalesced 512 B load per wave.
__global__ __launch_bounds__(256) void emb_gather_sum_bf16(
    const int*            __restrict__ indices,  // [N_TOKENS][N_FEATURES]
    const unsigned short* __restrict__ tables,   // [N_FEATURES][VOCAB][EMB_DIM] bf16
    float*                __restrict__ out)      // [N_TOKENS][EMB_DIM]
{
    const int gid = blockIdx.x * blockDim.x + threadIdx.x;
    const int t   = gid >> 6;            // token (wave-uniform)
    const int c   = (gid & 63) << 2;     // dim offset, float4-aligned

    const int4 i0 = *reinterpret_cast<const int4*>(indices + t * N_FEATURES);
    const int4 i1 = *reinterpret_cast<const int4*>(indices + t * N_FEATURES + 4);
    int ix[N_FEATURES] = { i0.x, i0.y, i0.z, i0.w, i1.x, i1.y, i1.z, i1.w };

    float4 acc = make_float4(0.f, 0.f, 0.f, 0.f);
#pragma unroll
    for (int f = 0; f < N_FEATURES; ++f) {
        const uint2 u = *reinterpret_cast<const uint2*>(
            tables + ((size_t)f * VOCAB + (size_t)ix[f]) * EMB_DIM + c);
        acc.x += __uint_as_float(u.x << 16);
        acc.y += __uint_as_float(u.x & 0xFFFF0000u);
        acc.z += __uint_as_float(u.y << 16);
        acc.w += __uint_as_float(u.y & 0xFFFF0000u);
    }

    *reinterpret_cast<float4*>(out + (size_t)t * EMB_DIM + c) = acc;
}

// ---------- fallback: fp32 gather (if ws too small) ----------
__global__ __launch_bounds__(256) void emb_gather_sum_f32(
    const int*   __restrict__ indices,
    const float* __restrict__ tables,
    float*       __restrict__ out)
{
    const int gid = blockIdx.x * blockDim.x + threadIdx.x;
    const int t   = gid >> 6;
    const int c   = (gid & 63) << 2;

    const int* __restrict__ idx = indices + t * N_FEATURES;
    float4 acc = make_float4(0.f, 0.f, 0.f, 0.f);
#pragma unroll
    for (int f = 0; f < N_FEATURES; ++f) {
        const int ix = idx[f];
        const float4 v = *reinterpret_cast<const float4*>(
            tables + ((size_t)f * VOCAB + (size_t)ix) * EMB_DIM + c);
        acc.x += v.x; acc.y += v.y; acc.z += v.z; acc.w += v.w;
    }
    *reinterpret_cast<float4*>(out + (size_t)t * EMB_DIM + c) = acc;
}

extern "C" void kernel_launch(void* const* d_in, const int* in_sizes, int n_in,
                              void* d_out, int out_size, void* d_ws, size_t ws_size,
                              hipStream_t stream) {
    const int*   indices = (const int*)d_in[0];
    const float* tables  = (const float*)d_in[1];
    float*       out     = (float*)d_out;

    const size_t need = (size_t)TABLE_ELEMS * sizeof(unsigned short);

    const int total_threads = N_TOKENS * 64;     // 4,194,304
    const int block = 256;
    const int grid  = total_threads / block;     // 16384

    if (ws_size >= need) {
        unsigned short* tb16 = (unsigned short*)d_ws;
        const int cvt_threads = (TABLE_ELEMS + 3) / 4;
        cvt_table_bf16<<<(cvt_threads + 255) / 256, 256, 0, stream>>>(
            tables, tb16, TABLE_ELEMS);
        emb_gather_sum_bf16<<<grid, block, 0, stream>>>(indices, tb16, out);
    } else {
        emb_gather_sum_f32<<<grid, block, 0, stream>>>(indices, tables, out);
    }
}

// Round 3
// 32.851 us; speedup vs baseline: 1.6457x; 1.1075x over previous
//
#include <hip/hip_runtime.h>

constexpr int N_TOKENS   = 65536;
constexpr int N_FEATURES = 8;
constexpr int VOCAB      = 1026;
constexpr int EMB_DIM    = 256;
constexpr int TABLE_ELEMS = N_FEATURES * VOCAB * EMB_DIM;   // 2,101,248

using v4f = __attribute__((ext_vector_type(4))) float;

// ---------- prep: fp32 table -> bf16 (RNE) into workspace ----------
__global__ __launch_bounds__(256) void cvt_table_bf16(
    const float* __restrict__ src, unsigned short* __restrict__ dst, int n)
{
    int i = (blockIdx.x * blockDim.x + threadIdx.x) * 4;
    if (i + 3 >= n) {
        for (int k = 0; i + k < n; ++k) {
            unsigned int x = __float_as_uint(src[i + k]);
            unsigned int r = x + 0x7FFFu + ((x >> 16) & 1u);
            dst[i + k] = (unsigned short)(r >> 16);
        }
        return;
    }
    const float4 v = *reinterpret_cast<const float4*>(src + i);
    ushort4 o;
    unsigned int x;
    x = __float_as_uint(v.x); o.x = (unsigned short)((x + 0x7FFFu + ((x >> 16) & 1u)) >> 16);
    x = __float_as_uint(v.y); o.y = (unsigned short)((x + 0x7FFFu + ((x >> 16) & 1u)) >> 16);
    x = __float_as_uint(v.z); o.z = (unsigned short)((x + 0x7FFFu + ((x >> 16) & 1u)) >> 16);
    x = __float_as_uint(v.w); o.w = (unsigned short)((x + 0x7FFFu + ((x >> 16) & 1u)) >> 16);
    *reinterpret_cast<ushort4*>(dst + i) = o;
}

// ---------- main: gather-sum from bf16 table ----------
// 32 lanes per token (a wave serves 2 tokens). Each lane loads a 16 B uint4
// (8 bf16 dims) per feature -> one 1 KiB coalesced load per wave per feature.
// Output stores are non-temporal so the 64 MiB write stream doesn't evict
// the ~4 MiB bf16 table from per-XCD L2.
__global__ __launch_bounds__(256) void emb_gather_sum_bf16(
    const int*            __restrict__ indices,  // [N_TOKENS][N_FEATURES]
    const unsigned short* __restrict__ tables,   // [N_FEATURES][VOCAB][EMB_DIM] bf16
    float*                __restrict__ out)      // [N_TOKENS][EMB_DIM]
{
    const int gid = blockIdx.x * blockDim.x + threadIdx.x;
    const int tok = gid >> 5;            // token (uniform per 32-lane half)
    const int q   = gid & 31;            // dim chunk: 8 bf16 elems, 16 B

    const int4 i0 = *reinterpret_cast<const int4*>(indices + tok * N_FEATURES);
    const int4 i1 = *reinterpret_cast<const int4*>(indices + tok * N_FEATURES + 4);
    const int ix[N_FEATURES] = { i0.x, i0.y, i0.z, i0.w, i1.x, i1.y, i1.z, i1.w };

    float acc[8] = {0.f, 0.f, 0.f, 0.f, 0.f, 0.f, 0.f, 0.f};
#pragma unroll
    for (int f = 0; f < N_FEATURES; ++f) {
        const uint4 u = *reinterpret_cast<const uint4*>(
            tables + ((size_t)f * VOCAB + (size_t)ix[f]) * EMB_DIM + q * 8);
        acc[0] += __uint_as_float(u.x << 16);
        acc[1] += __uint_as_float(u.x & 0xFFFF0000u);
        acc[2] += __uint_as_float(u.y << 16);
        acc[3] += __uint_as_float(u.y & 0xFFFF0000u);
        acc[4] += __uint_as_float(u.z << 16);
        acc[5] += __uint_as_float(u.z & 0xFFFF0000u);
        acc[6] += __uint_as_float(u.w << 16);
        acc[7] += __uint_as_float(u.w & 0xFFFF0000u);
    }

    v4f lo = { acc[0], acc[1], acc[2], acc[3] };
    v4f hi = { acc[4], acc[5], acc[6], acc[7] };
    v4f* dst = reinterpret_cast<v4f*>(out + (size_t)tok * EMB_DIM + q * 8);
    __builtin_nontemporal_store(lo, dst);
    __builtin_nontemporal_store(hi, dst + 1);
}

// ---------- fallback: fp32 gather (if ws too small) ----------
__global__ __launch_bounds__(256) void emb_gather_sum_f32(
    const int*   __restrict__ indices,
    const float* __restrict__ tables,
    float*       __restrict__ out)
{
    const int gid = blockIdx.x * blockDim.x + threadIdx.x;
    const int t   = gid >> 6;
    const int c   = (gid & 63) << 2;

    const int* __restrict__ idx = indices + t * N_FEATURES;
    float4 acc = make_float4(0.f, 0.f, 0.f, 0.f);
#pragma unroll
    for (int f = 0; f < N_FEATURES; ++f) {
        const int ixv = idx[f];
        const float4 v = *reinterpret_cast<const float4*>(
            tables + ((size_t)f * VOCAB + (size_t)ixv) * EMB_DIM + c);
        acc.x += v.x; acc.y += v.y; acc.z += v.z; acc.w += v.w;
    }
    *reinterpret_cast<float4*>(out + (size_t)t * EMB_DIM + c) = acc;
}

extern "C" void kernel_launch(void* const* d_in, const int* in_sizes, int n_in,
                              void* d_out, int out_size, void* d_ws, size_t ws_size,
                              hipStream_t stream) {
    const int*   indices = (const int*)d_in[0];
    const float* tables  = (const float*)d_in[1];
    float*       out     = (float*)d_out;

    const size_t need = (size_t)TABLE_ELEMS * sizeof(unsigned short);

    if (ws_size >= need) {
        unsigned short* tb16 = (unsigned short*)d_ws;
        const int cvt_threads = (TABLE_ELEMS + 3) / 4;
        cvt_table_bf16<<<(cvt_threads + 255) / 256, 256, 0, stream>>>(
            tables, tb16, TABLE_ELEMS);

        const int total_threads = N_TOKENS * 32;    // 2,097,152
        const int block = 256;
        emb_gather_sum_bf16<<<total_threads / block, block, 0, stream>>>(
            indices, tb16, out);
    } else {
        const int total_threads = N_TOKENS * 64;
        const int block = 256;
        emb_gather_sum_f32<<<total_threads / block, block, 0, stream>>>(
            indices, tables, out);
    }
}

// Round 4
// 32.251 us; speedup vs baseline: 1.6764x; 1.0186x over previous
//
#include <hip/hip_runtime.h>

constexpr int N_TOKENS   = 65536;
constexpr int N_FEATURES = 8;
constexpr int VOCAB      = 1026;
constexpr int EMB_DIM    = 256;
constexpr int TABLE_ELEMS = N_FEATURES * VOCAB * EMB_DIM;   // 2,101,248

using v4f = __attribute__((ext_vector_type(4))) float;

// ---------- prep: fp32 table -> bf16 (RNE) into workspace ----------
__global__ __launch_bounds__(256) void cvt_table_bf16(
    const float* __restrict__ src, unsigned short* __restrict__ dst, int n)
{
    int i = (blockIdx.x * blockDim.x + threadIdx.x) * 4;
    if (i + 3 >= n) {
        for (int k = 0; i + k < n; ++k) {
            unsigned int x = __float_as_uint(src[i + k]);
            unsigned int r = x + 0x7FFFu + ((x >> 16) & 1u);
            dst[i + k] = (unsigned short)(r >> 16);
        }
        return;
    }
    const float4 v = *reinterpret_cast<const float4*>(src + i);
    ushort4 o;
    unsigned int x;
    x = __float_as_uint(v.x); o.x = (unsigned short)((x + 0x7FFFu + ((x >> 16) & 1u)) >> 16);
    x = __float_as_uint(v.y); o.y = (unsigned short)((x + 0x7FFFu + ((x >> 16) & 1u)) >> 16);
    x = __float_as_uint(v.z); o.z = (unsigned short)((x + 0x7FFFu + ((x >> 16) & 1u)) >> 16);
    x = __float_as_uint(v.w); o.w = (unsigned short)((x + 0x7FFFu + ((x >> 16) & 1u)) >> 16);
    *reinterpret_cast<ushort4*>(dst + i) = o;
}

// ---------- main: gather-sum from bf16 table ----------
// 32 lanes per token; 8 tokens per 256-thread block. Indices staged via LDS:
// 16 threads load int4 each (256 B), then all lanes read via LDS broadcast —
// removes the 32x-redundant vector-path index loads (17% of datapath bytes).
// Gathers are 16 B/lane dwordx4; output stores non-temporal (don't evict the
// ~4.2 MB bf16 table from per-XCD L2).
__global__ __launch_bounds__(256) void emb_gather_sum_bf16(
    const int*            __restrict__ indices,  // [N_TOKENS][N_FEATURES]
    const unsigned short* __restrict__ tables,   // [N_FEATURES][VOCAB][EMB_DIM] bf16
    float*                __restrict__ out)      // [N_TOKENS][EMB_DIM]
{
    __shared__ int sidx[8 * N_FEATURES];         // 8 tokens x 8 features

    const int tid     = threadIdx.x;
    const int tok_blk = blockIdx.x * 8;

    if (tid < 16) {
        reinterpret_cast<int4*>(sidx)[tid] =
            reinterpret_cast<const int4*>(indices + (size_t)tok_blk * N_FEATURES)[tid];
    }
    __syncthreads();

    const int tl  = tid >> 5;                    // token within block
    const int q   = tid & 31;                    // 16 B chunk within row
    const int tok = tok_blk + tl;
    const int* myidx = sidx + tl * N_FEATURES;

    float acc[8] = {0.f, 0.f, 0.f, 0.f, 0.f, 0.f, 0.f, 0.f};
#pragma unroll
    for (int f = 0; f < N_FEATURES; ++f) {
        const uint4 u = *reinterpret_cast<const uint4*>(
            tables + ((size_t)f * VOCAB + (size_t)myidx[f]) * EMB_DIM + q * 8);
        acc[0] += __uint_as_float(u.x << 16);
        acc[1] += __uint_as_float(u.x & 0xFFFF0000u);
        acc[2] += __uint_as_float(u.y << 16);
        acc[3] += __uint_as_float(u.y & 0xFFFF0000u);
        acc[4] += __uint_as_float(u.z << 16);
        acc[5] += __uint_as_float(u.z & 0xFFFF0000u);
        acc[6] += __uint_as_float(u.w << 16);
        acc[7] += __uint_as_float(u.w & 0xFFFF0000u);
    }

    v4f lo = { acc[0], acc[1], acc[2], acc[3] };
    v4f hi = { acc[4], acc[5], acc[6], acc[7] };
    v4f* dst = reinterpret_cast<v4f*>(out + (size_t)tok * EMB_DIM + q * 8);
    __builtin_nontemporal_store(lo, dst);
    __builtin_nontemporal_store(hi, dst + 1);
}

// ---------- fallback: fp32 gather (if ws too small) ----------
__global__ __launch_bounds__(256) void emb_gather_sum_f32(
    const int*   __restrict__ indices,
    const float* __restrict__ tables,
    float*       __restrict__ out)
{
    const int gid = blockIdx.x * blockDim.x + threadIdx.x;
    const int t   = gid >> 6;
    const int c   = (gid & 63) << 2;

    const int* __restrict__ idx = indices + t * N_FEATURES;
    float4 acc = make_float4(0.f, 0.f, 0.f, 0.f);
#pragma unroll
    for (int f = 0; f < N_FEATURES; ++f) {
        const int ixv = idx[f];
        const float4 v = *reinterpret_cast<const float4*>(
            tables + ((size_t)f * VOCAB + (size_t)ixv) * EMB_DIM + c);
        acc.x += v.x; acc.y += v.y; acc.z += v.z; acc.w += v.w;
    }
    *reinterpret_cast<float4*>(out + (size_t)t * EMB_DIM + c) = acc;
}

extern "C" void kernel_launch(void* const* d_in, const int* in_sizes, int n_in,
                              void* d_out, int out_size, void* d_ws, size_t ws_size,
                              hipStream_t stream) {
    const int*   indices = (const int*)d_in[0];
    const float* tables  = (const float*)d_in[1];
    float*       out     = (float*)d_out;

    const size_t need = (size_t)TABLE_ELEMS * sizeof(unsigned short);

    if (ws_size >= need) {
        unsigned short* tb16 = (unsigned short*)d_ws;
        const int cvt_threads = (TABLE_ELEMS + 3) / 4;
        cvt_table_bf16<<<(cvt_threads + 255) / 256, 256, 0, stream>>>(
            tables, tb16, TABLE_ELEMS);

        const int total_threads = N_TOKENS * 32;    // 2,097,152
        const int block = 256;
        emb_gather_sum_bf16<<<total_threads / block, block, 0, stream>>>(
            indices, tb16, out);
    } else {
        const int total_threads = N_TOKENS * 64;
        const int block = 256;
        emb_gather_sum_f32<<<total_threads / block, block, 0, stream>>>(
            indices, tables, out);
    }
}